// Round 7
// baseline (191.584 us; speedup 1.0000x reference)
//
#include <hip/hip_runtime.h>
#include <hip/hip_bf16.h>

#define BB 4
#define TT 2048
#define CC 1024
#define HH 16
#define HD 64
#define NQ (3*CC)
// 1/sqrt(64) * log2(e): attention done in exp2 domain
#define QSCALE 0.18033688011112042f

typedef __attribute__((ext_vector_type(8))) short bf16x8;
typedef __attribute__((ext_vector_type(4))) short short4_t;
typedef __attribute__((ext_vector_type(4))) float f32x4;

#define MFMA(a,b,c) __builtin_amdgcn_mfma_f32_16x16x32_bf16(a,b,c,0,0,0)

// async global->LDS, 16B per lane; LDS dest is wave-uniform base + lane*16
#define ASYNC16(gsrc, ldst) \
  __builtin_amdgcn_global_load_lds((const __attribute__((address_space(1))) void*)(gsrc), \
                                   (__attribute__((address_space(3))) void*)(ldst), 16, 0, 0)

// row-swizzle for 64-short-stride LDS tiles (16B-chunk granularity)
#define SWZA(row) (((((row) & 7) + (((row) >> 3) & 3)) & 7) << 3)

static __device__ __forceinline__ short f2bf(float f){
    union { float f; unsigned u; } v; v.f = f;
    unsigned r = v.u + 0x7FFFu + ((v.u >> 16) & 1u);   // RNE
    return (short)(r >> 16);
}
// fast round (non-negative finite values only)
static __device__ __forceinline__ short f2bfu(float f){
    union { float f; unsigned u; } v; v.f = f;
    return (short)((v.u + 0x8000u) >> 16);
}

// ---------------- prepass: x fp32 -> bf16 (row-major, unchanged layout)
__global__ __launch_bounds__(256)
void convert_x(const float* __restrict__ x, short* __restrict__ xb)
{
    int i = (blockIdx.x * 256 + threadIdx.x) * 8;
    float4 a = *reinterpret_cast<const float4*>(&x[i]);
    float4 b = *reinterpret_cast<const float4*>(&x[i+4]);
    bf16x8 o = { f2bf(a.x), f2bf(a.y), f2bf(a.z), f2bf(a.w),
                 f2bf(b.x), f2bf(b.y), f2bf(b.z), f2bf(b.w) };
    *reinterpret_cast<bf16x8*>(&xb[i]) = o;
}

// ---------------- prepass: w fp32 [K=1024][N] -> wT bf16 [N][1024]
__global__ __launch_bounds__(256)
void transpose_w(const float* __restrict__ w, short* __restrict__ wT, int N)
{
    __shared__ short sm[64*72];
    const int kt0 = blockIdx.x * 64;
    const int nt0 = blockIdx.y * 64;
    const int t = threadIdx.x;
    const int r  = t >> 4;
    const int c4 = (t & 15) * 4;
#pragma unroll
    for (int it = 0; it < 4; it++){
        int k = r + it*16;
        float4 v = *reinterpret_cast<const float4*>(&w[(size_t)(kt0 + k)*N + nt0 + c4]);
        sm[(c4+0)*72 + k] = f2bf(v.x);
        sm[(c4+1)*72 + k] = f2bf(v.y);
        sm[(c4+2)*72 + k] = f2bf(v.z);
        sm[(c4+3)*72 + k] = f2bf(v.w);
    }
    __syncthreads();
    const int nl = t >> 2;
    const int kc = (t & 3) * 16;
    bf16x8 o0 = *reinterpret_cast<const bf16x8*>(&sm[nl*72 + kc]);
    bf16x8 o1 = *reinterpret_cast<const bf16x8*>(&sm[nl*72 + kc + 8]);
    short* dst = &wT[(size_t)(nt0 + nl)*CC + kt0 + kc];
    *reinterpret_cast<bf16x8*>(dst)     = o0;
    *reinterpret_cast<bf16x8*>(dst + 8) = o1;
}

// ---------------- prepass: vb [bh][T][64] -> vtb [bh][64][T]  (per-head V transpose)
__global__ __launch_bounds__(256)
void transpose_v(const short* __restrict__ vb, short* __restrict__ vtb)
{
    __shared__ short sm[64*72];
    const int bh = blockIdx.x;
    const int t0 = blockIdx.y * 64;
    const int t = threadIdx.x;
    const int r   = t >> 2;          // 0..63
    const int c16 = (t & 3) * 16;
    const short* src = vb + (size_t)bh*TT*HD + (size_t)t0*HD;
    bf16x8 a0 = *reinterpret_cast<const bf16x8*>(&src[r*HD + c16]);
    bf16x8 a1 = *reinterpret_cast<const bf16x8*>(&src[r*HD + c16 + 8]);
#pragma unroll
    for (int j=0;j<8;j++){
        sm[(c16+j)*72 + r]   = a0[j];
        sm[(c16+8+j)*72 + r] = a1[j];
    }
    __syncthreads();
    bf16x8 o0 = *reinterpret_cast<const bf16x8*>(&sm[r*72 + c16]);
    bf16x8 o1 = *reinterpret_cast<const bf16x8*>(&sm[r*72 + c16 + 8]);
    short* dst = vtb + (size_t)bh*HD*TT + (size_t)r*TT + t0 + c16;
    *reinterpret_cast<bf16x8*>(dst)     = o0;
    *reinterpret_cast<bf16x8*>(dst + 8) = o1;
}

// ---------------- QKV GEMM (bf16): xb [8192,1024] @ wT^T -> q/k/v bf16 [B,H,T,HD]
__global__ __launch_bounds__(256, 2)
void qkv_gemm(const short* __restrict__ xb, const short* __restrict__ wT,
              const float* __restrict__ bias,
              short* __restrict__ qb, short* __restrict__ kb, short* __restrict__ vb)
{
    __shared__ short As[128*64];
    __shared__ short Bs[128*64];
    const int bid = blockIdx.x;
    const int swz = (bid & 7) * 192 + (bid >> 3);   // 1536 blocks, bijective XCD swizzle
    const int bm = swz / (NQ/128);
    const int bn = swz % (NQ/128);
    const int m0 = bm*128, n0 = bn*128;
    const int t  = threadIdx.x;
    const int wid = t >> 6, lane = t & 63;
    const int wr = wid >> 1, wc = wid & 1;
    const int l15 = lane & 15, lh = lane >> 4;

    f32x4 acc[4][4];
#pragma unroll
    for (int i=0;i<4;i++)
#pragma unroll
      for (int j=0;j<4;j++) acc[i][j] = (f32x4)0.f;

    for (int k0 = 0; k0 < CC; k0 += 64) {
        __syncthreads();
#pragma unroll
        for (int i=0;i<4;i++){
            int u   = (wid*4 + i)*64 + lane;
            int row = u >> 3, c = u & 7;
            int cs  = c ^ (row & 7);      // inverse-swizzled source chunk
            ASYNC16(&xb[(size_t)(m0+row)*CC + k0 + cs*8], &As[(wid*4+i)*512]);
            ASYNC16(&wT[(size_t)(n0+row)*CC + k0 + cs*8], &Bs[(wid*4+i)*512]);
        }
        __syncthreads();
#pragma unroll
        for (int ks=0;ks<2;ks++){
            bf16x8 a[4], b[4];
#pragma unroll
            for (int m=0;m<4;m++){
                int row = wr*64 + m*16 + l15;
                a[m] = *reinterpret_cast<const bf16x8*>(&As[row*64 + (((ks<<2)|lh) ^ (row&7))*8]);
            }
#pragma unroll
            for (int n=0;n<4;n++){
                int col = wc*64 + n*16 + l15;
                b[n] = *reinterpret_cast<const bf16x8*>(&Bs[col*64 + (((ks<<2)|lh) ^ (col&7))*8]);
            }
#pragma unroll
            for (int m=0;m<4;m++)
#pragma unroll
              for (int n=0;n<4;n++)
                acc[m][n] = MFMA(a[m], b[n], acc[m][n]);
        }
    }

    // epilogue: scatter into q/k/v [B,H,T,HD] bf16; fold exp2-domain scale into q
#pragma unroll
    for (int n=0;n<4;n++){
        int col = n0 + wc*64 + n*16 + l15;
        int sect = col >> 10;
        int cc = col & 1023;
        int h = cc >> 6, d = cc & 63;
        float bv = bias[col];
        short* dst = (sect==0) ? qb : (sect==1) ? kb : vb;
        float mul = (sect==0) ? QSCALE : 1.f;
#pragma unroll
        for (int m=0;m<4;m++)
#pragma unroll
          for (int r=0;r<4;r++){
            int row = m0 + wr*64 + m*16 + lh*4 + r;
            int b_ = row >> 11, tt_ = row & (TT-1);
            float v = (acc[m][n][r] + bv) * mul;
            dst[((size_t)(b_*HH + h)*TT + tt_)*HD + d] = f2bf(v);
          }
    }
}

// ---------------- Flash attention v7: paired 128-row q-tiles, swapped QK^T,
// K/V staged via global_load_lds (linear LDS dest + inverse-swizzled source),
// 2-phase double buffer, 3 blocks/CU.
__global__ __launch_bounds__(256, 3)
void attn_kernel(const short* __restrict__ qb, const short* __restrict__ kb,
                 const short* __restrict__ vtb, short* __restrict__ yb)
{
    __shared__ short Ks[2][64*64];   // [kv][d] bf16, SWZA chunk swizzle
    __shared__ short Vt[2][64*64];   // [d][kv] bf16, SWZA chunk swizzle
    __shared__ short Ps[4][32*64];   // per-wave P [qloc][kv] bf16, SWZA

    const int bh = blockIdx.x;       // 0..63 : id%8 == bh%8 -> same-head blocks share XCD
    const int p  = blockIdx.y;       // 0..7  : pair index
    const int b_ = bh >> 4, h = bh & 15;
    const short* qp  = qb  + (size_t)bh*TT*HD;
    const short* kp  = kb  + (size_t)bh*TT*HD;
    const short* vtp = vtb + (size_t)bh*HD*TT;   // [d][T]
    const int t = threadIdx.x, wid = t >> 6, lane = t & 63;
    const int l15 = lane & 15, lh = lane >> 4;

    // staging map: u = (wid*2+i)*64 + lane; row = u>>3, chunk = u&7 (16B chunks)
    const int su0 = (wid*2+0)*64 + lane;
    const int su1 = (wid*2+1)*64 + lane;
    const int sr0 = su0 >> 3, sc0 = (su0 & 7) ^ (SWZA(su0 >> 3) >> 3);
    const int sr1 = su1 >> 3, sc1 = (su1 & 7) ^ (SWZA(su1 >> 3) >> 3);

    const bf16x8 ones = { 0x3F80,0x3F80,0x3F80,0x3F80,0x3F80,0x3F80,0x3F80,0x3F80 };

    auto stage = [&](int buf, int kvbase){
        ASYNC16(&kp[(size_t)(kvbase+sr0)*HD + sc0*8], &Ks[buf][(wid*2+0)*512]);
        ASYNC16(&kp[(size_t)(kvbase+sr1)*HD + sc1*8], &Ks[buf][(wid*2+1)*512]);
        ASYNC16(&vtp[(size_t)sr0*TT + kvbase + sc0*8], &Vt[buf][(wid*2+0)*512]);
        ASYNC16(&vtp[(size_t)sr1*TT + kvbase + sc1*8], &Vt[buf][(wid*2+1)*512]);
    };

    for (int hf = 0; hf < 2; hf++){
        const int qt  = hf ? (15 - p) : p;      // q-tile of 128 rows
        const int wq0 = qt*128 + wid*32;        // this wave's first q row

        bf16x8 qf[2][2];
#pragma unroll
        for (int m=0;m<2;m++)
#pragma unroll
          for (int ks=0;ks<2;ks++)
            qf[m][ks] = *reinterpret_cast<const bf16x8*>(
                &qp[(size_t)(wq0 + m*16 + l15)*HD + ks*32 + lh*8]);

        f32x4 po[2][4];
        f32x4 pden[2];
#pragma unroll
        for (int m=0;m<2;m++){
            pden[m] = (f32x4)0.f;
#pragma unroll
            for (int n=0;n<4;n++) po[m][n] = (f32x4)0.f;
        }

        const int ntk = 2*(qt + 1);

        stage(0, 0);
        __syncthreads();   // implicit vmcnt(0) drain before barrier

        for (int kt = 0; kt < ntk; kt++){
            const int cur = kt & 1;
            const int kv0 = kt*64;
            if (kt+1 < ntk) stage(cur ^ 1, kv0 + 64);   // fly during compute

            if (kv0 <= wq0 + 31){     // wave-uniform causal activity test
                // S^T = K Q^T : per lane q = l15 (const), kv = f*16 + lh*4 + r
                f32x4 s[2][4];
#pragma unroll
                for (int m=0;m<2;m++)
#pragma unroll
                  for (int f=0;f<4;f++) s[m][f] = (f32x4)0.f;
                __builtin_amdgcn_s_setprio(1);
#pragma unroll
                for (int ks=0;ks<2;ks++){
#pragma unroll
                    for (int f=0;f<4;f++){
                        int kvr = f*16 + l15;
                        bf16x8 kf = *reinterpret_cast<const bf16x8*>(
                            &Ks[cur][(kvr*64 + ks*32 + lh*8) ^ SWZA(kvr)]);
                        s[0][f] = MFMA(kf, qf[0][ks], s[0][f]);
                        s[1][f] = MFMA(kf, qf[1][ks], s[1][f]);
                    }
                }
                __builtin_amdgcn_s_setprio(0);
                // causal mask (straddling tiles only): q is per-lane scalar
#pragma unroll
                for (int m=0;m<2;m++){
                    if (kv0 + 63 > wq0 + m*16){
                        int qm = wq0 + m*16 + l15;
#pragma unroll
                        for (int f=0;f<4;f++)
#pragma unroll
                          for (int r=0;r<4;r++){
                            int kv = kv0 + f*16 + lh*4 + r;
                            if (kv > qm) s[m][f][r] = -1e30f;
                          }
                    }
                }
                // P = exp2(S'), pack 4 consecutive kv -> one b64 LDS write
#pragma unroll
                for (int m=0;m<2;m++){
                    int qloc = m*16 + l15;
                    int rowswz = SWZA(qloc);
#pragma unroll
                    for (int f=0;f<4;f++){
                        short4_t pk = { f2bfu(exp2f(s[m][f][0])),
                                        f2bfu(exp2f(s[m][f][1])),
                                        f2bfu(exp2f(s[m][f][2])),
                                        f2bfu(exp2f(s[m][f][3])) };
                        int idx = (qloc*64 + f*16 + lh*4) ^ rowswz;
                        *reinterpret_cast<short4_t*>(&Ps[wid][idx]) = pk;
                    }
                }
                // O += P V ; den += P * 1  (ones-column via constant B-fragment)
                __builtin_amdgcn_s_setprio(1);
#pragma unroll
                for (int ks2=0;ks2<2;ks2++){
                    bf16x8 pa[2];
#pragma unroll
                    for (int m=0;m<2;m++){
                        int qloc = m*16 + l15;
                        pa[m] = *reinterpret_cast<const bf16x8*>(
                            &Ps[wid][(qloc*64 + ks2*32 + lh*8) ^ SWZA(qloc)]);
                    }
                    pden[0] = MFMA(pa[0], ones, pden[0]);
                    pden[1] = MFMA(pa[1], ones, pden[1]);
#pragma unroll
                    for (int n=0;n<4;n++){
                        int dd = n*16 + l15;
                        bf16x8 vf = *reinterpret_cast<const bf16x8*>(
                            &Vt[cur][(dd*64 + ks2*32 + lh*8) ^ SWZA(dd)]);
                        po[0][n] = MFMA(pa[0], vf, po[0][n]);
                        po[1][n] = MFMA(pa[1], vf, po[1][n]);
                    }
                }
                __builtin_amdgcn_s_setprio(0);
            }

            __syncthreads();   // drains staged loads (vmcnt) + publishes next buffer
        }

        // epilogue -> y [B,T,C] bf16
#pragma unroll
        for (int m=0;m<2;m++){
            float rcp[4];
#pragma unroll
            for (int r=0;r<4;r++) rcp[r] = 1.f / pden[m][r];
#pragma unroll
            for (int n=0;n<4;n++)
#pragma unroll
              for (int r=0;r<4;r++){
                int q = wq0 + m*16 + lh*4 + r;
                int dd = n*16 + l15;
                yb[(size_t)(b_*TT + q)*CC + h*HD + dd] = f2bf(po[m][n][r] * rcp[r]);
              }
        }
    }
}

// ---------------- Output projection (bf16): y [8192,1024] @ wpT^T + bias -> fp32 out
__global__ __launch_bounds__(256, 2)
void proj_gemm(const short* __restrict__ y, const short* __restrict__ wpT,
               const float* __restrict__ bias, float* __restrict__ out)
{
    __shared__ short As[128*64];
    __shared__ short Bs[128*64];
    const int bid = blockIdx.x;
    const int swz = (bid & 7) * 64 + (bid >> 3);   // 512 blocks
    const int bm = swz >> 3, bn = swz & 7;
    const int m0 = bm*128, n0 = bn*128;
    const int t  = threadIdx.x;
    const int wid = t >> 6, lane = t & 63;
    const int wr = wid >> 1, wc = wid & 1;
    const int l15 = lane & 15, lh = lane >> 4;

    f32x4 acc[4][4];
#pragma unroll
    for (int i=0;i<4;i++)
#pragma unroll
      for (int j=0;j<4;j++) acc[i][j] = (f32x4)0.f;

    for (int k0 = 0; k0 < CC; k0 += 64) {
        __syncthreads();
#pragma unroll
        for (int i=0;i<4;i++){
            int u   = (wid*4 + i)*64 + lane;
            int row = u >> 3, c = u & 7;
            int cs  = c ^ (row & 7);
            ASYNC16(&y[(size_t)(m0+row)*CC + k0 + cs*8],   &As[(wid*4+i)*512]);
            ASYNC16(&wpT[(size_t)(n0+row)*CC + k0 + cs*8], &Bs[(wid*4+i)*512]);
        }
        __syncthreads();
#pragma unroll
        for (int ks=0;ks<2;ks++){
            bf16x8 a[4], b[4];
#pragma unroll
            for (int m=0;m<4;m++){
                int row = wr*64 + m*16 + l15;
                a[m] = *reinterpret_cast<const bf16x8*>(&As[row*64 + (((ks<<2)|lh) ^ (row&7))*8]);
            }
#pragma unroll
            for (int n=0;n<4;n++){
                int col = wc*64 + n*16 + l15;
                b[n] = *reinterpret_cast<const bf16x8*>(&Bs[col*64 + (((ks<<2)|lh) ^ (col&7))*8]);
            }
#pragma unroll
            for (int m=0;m<4;m++)
#pragma unroll
              for (int n=0;n<4;n++)
                acc[m][n] = MFMA(a[m], b[n], acc[m][n]);
        }
    }

#pragma unroll
    for (int n=0;n<4;n++){
        int col = n0 + wc*64 + n*16 + l15;
        float bv = bias[col];
#pragma unroll
        for (int m=0;m<4;m++)
#pragma unroll
          for (int r=0;r<4;r++){
            int row = m0 + wr*64 + m*16 + lh*4 + r;
            out[(size_t)row*CC + col] = acc[m][n][r] + bv;
          }
    }
}

extern "C" void kernel_launch(void* const* d_in, const int* in_sizes, int n_in,
                              void* d_out, int out_size, void* d_ws, size_t ws_size,
                              hipStream_t stream) {
    const float* x      = (const float*)d_in[0];
    const float* w_attn = (const float*)d_in[1];
    const float* b_attn = (const float*)d_in[2];
    const float* w_proj = (const float*)d_in[3];
    const float* b_proj = (const float*)d_in[4];
    float* out = (float*)d_out;

    const size_t S = (size_t)BB*TT*CC;   // 8.4M elems
    short* qb  = (short*)d_ws;           // bf16 [B,H,T,HD]
    short* kb  = qb + S;
    short* vb  = kb + S;
    short* yx  = vb + S;                 // x-bf16 during prepass+qkv; y-bf16 after attn
    short* wT  = yx + S;                 // bf16 [3072][1024]
    short* wpT = wT + (size_t)NQ*CC;     // bf16 [1024][1024]
    short* vtb = wpT + (size_t)CC*CC;    // bf16 [B,H,HD,T]  (V transposed per head)

    convert_x<<<dim3(S/(256*8)), 256, 0, stream>>>(x, yx);
    transpose_w<<<dim3(CC/64, NQ/64), 256, 0, stream>>>(w_attn, wT, NQ);
    transpose_w<<<dim3(CC/64, CC/64), 256, 0, stream>>>(w_proj, wpT, CC);
    qkv_gemm<<<dim3((BB*TT/128)*(NQ/128)), 256, 0, stream>>>(yx, wT, b_attn, qb, kb, vb);
    transpose_v<<<dim3(BB*HH, TT/64), 256, 0, stream>>>(vb, vtb);
    attn_kernel<<<dim3(BB*HH, TT/256), 256, 0, stream>>>(qb, kb, vtb, yx);
    proj_gemm<<<dim3((BB*TT/128)*(CC/128)), 256, 0, stream>>>(yx, wpT, b_proj, out);
}

// Round 8
// 179.880 us; speedup vs baseline: 1.0651x; 1.0651x over previous
//
#include <hip/hip_runtime.h>
#include <hip/hip_bf16.h>

#define BB 4
#define TT 2048
#define CC 1024
#define HH 16
#define HD 64
#define NQ (3*CC)
// 1/sqrt(64) * log2(e): attention done in exp2 domain
#define QSCALE 0.18033688011112042f

typedef __attribute__((ext_vector_type(8))) short bf16x8;
typedef __attribute__((ext_vector_type(4))) short short4_t;
typedef __attribute__((ext_vector_type(4))) float f32x4;

#define MFMA(a,b,c) __builtin_amdgcn_mfma_f32_16x16x32_bf16(a,b,c,0,0,0)

// async global->LDS, 16B per lane; LDS dest is wave-uniform base + lane*16
#define ASYNC16(gsrc, ldst) \
  __builtin_amdgcn_global_load_lds((const __attribute__((address_space(1))) void*)(gsrc), \
                                   (__attribute__((address_space(3))) void*)(ldst), 16, 0, 0)

// row-swizzle for 64-short-stride LDS tiles (16B-chunk granularity)
#define SWZA(row) (((((row) & 7) + (((row) >> 3) & 3)) & 7) << 3)

static __device__ __forceinline__ short f2bf(float f){
    union { float f; unsigned u; } v; v.f = f;
    unsigned r = v.u + 0x7FFFu + ((v.u >> 16) & 1u);   // RNE
    return (short)(r >> 16);
}
// packed f32x2 -> bf16x2 (RNE), single HW instruction
static __device__ __forceinline__ unsigned cvtpk(float a, float b){
    unsigned r;
    asm("v_cvt_pk_bf16_f32 %0, %1, %2" : "=v"(r) : "v"(a), "v"(b));
    return r;
}

// ---------------- prepass: x fp32 -> bf16 (row-major, unchanged layout)
__global__ __launch_bounds__(256)
void convert_x(const float* __restrict__ x, short* __restrict__ xb)
{
    int i = (blockIdx.x * 256 + threadIdx.x) * 8;
    float4 a = *reinterpret_cast<const float4*>(&x[i]);
    float4 b = *reinterpret_cast<const float4*>(&x[i+4]);
    bf16x8 o = { f2bf(a.x), f2bf(a.y), f2bf(a.z), f2bf(a.w),
                 f2bf(b.x), f2bf(b.y), f2bf(b.z), f2bf(b.w) };
    *reinterpret_cast<bf16x8*>(&xb[i]) = o;
}

// ---------------- prepass: w fp32 [K=1024][N] -> wT bf16 [N][1024]
__global__ __launch_bounds__(256)
void transpose_w(const float* __restrict__ w, short* __restrict__ wT, int N)
{
    __shared__ short sm[64*72];
    const int kt0 = blockIdx.x * 64;
    const int nt0 = blockIdx.y * 64;
    const int t = threadIdx.x;
    const int r  = t >> 4;
    const int c4 = (t & 15) * 4;
#pragma unroll
    for (int it = 0; it < 4; it++){
        int k = r + it*16;
        float4 v = *reinterpret_cast<const float4*>(&w[(size_t)(kt0 + k)*N + nt0 + c4]);
        sm[(c4+0)*72 + k] = f2bf(v.x);
        sm[(c4+1)*72 + k] = f2bf(v.y);
        sm[(c4+2)*72 + k] = f2bf(v.z);
        sm[(c4+3)*72 + k] = f2bf(v.w);
    }
    __syncthreads();
    const int nl = t >> 2;
    const int kc = (t & 3) * 16;
    bf16x8 o0 = *reinterpret_cast<const bf16x8*>(&sm[nl*72 + kc]);
    bf16x8 o1 = *reinterpret_cast<const bf16x8*>(&sm[nl*72 + kc + 8]);
    short* dst = &wT[(size_t)(nt0 + nl)*CC + kt0 + kc];
    *reinterpret_cast<bf16x8*>(dst)     = o0;
    *reinterpret_cast<bf16x8*>(dst + 8) = o1;
}

// ---------------- prepass: vb [bh][T][64] -> vtb [bh][64][T]  (per-head V transpose)
__global__ __launch_bounds__(256)
void transpose_v(const short* __restrict__ vb, short* __restrict__ vtb)
{
    __shared__ short sm[64*72];
    const int bh = blockIdx.x;
    const int t0 = blockIdx.y * 64;
    const int t = threadIdx.x;
    const int r   = t >> 2;          // 0..63
    const int c16 = (t & 3) * 16;
    const short* src = vb + (size_t)bh*TT*HD + (size_t)t0*HD;
    bf16x8 a0 = *reinterpret_cast<const bf16x8*>(&src[r*HD + c16]);
    bf16x8 a1 = *reinterpret_cast<const bf16x8*>(&src[r*HD + c16 + 8]);
#pragma unroll
    for (int j=0;j<8;j++){
        sm[(c16+j)*72 + r]   = a0[j];
        sm[(c16+8+j)*72 + r] = a1[j];
    }
    __syncthreads();
    bf16x8 o0 = *reinterpret_cast<const bf16x8*>(&sm[r*72 + c16]);
    bf16x8 o1 = *reinterpret_cast<const bf16x8*>(&sm[r*72 + c16 + 8]);
    short* dst = vtb + (size_t)bh*HD*TT + (size_t)r*TT + t0 + c16;
    *reinterpret_cast<bf16x8*>(dst)     = o0;
    *reinterpret_cast<bf16x8*>(dst + 8) = o1;
}

// ---------------- QKV GEMM (bf16): xb [8192,1024] @ wT^T -> q/k/v bf16 [B,H,T,HD]
__global__ __launch_bounds__(256, 2)
void qkv_gemm(const short* __restrict__ xb, const short* __restrict__ wT,
              const float* __restrict__ bias,
              short* __restrict__ qb, short* __restrict__ kb, short* __restrict__ vb)
{
    __shared__ short As[128*64];
    __shared__ short Bs[128*64];
    const int bid = blockIdx.x;
    const int swz = (bid & 7) * 192 + (bid >> 3);   // 1536 blocks, bijective XCD swizzle
    const int bm = swz / (NQ/128);
    const int bn = swz % (NQ/128);
    const int m0 = bm*128, n0 = bn*128;
    const int t  = threadIdx.x;
    const int wid = t >> 6, lane = t & 63;
    const int wr = wid >> 1, wc = wid & 1;
    const int l15 = lane & 15, lh = lane >> 4;

    f32x4 acc[4][4];
#pragma unroll
    for (int i=0;i<4;i++)
#pragma unroll
      for (int j=0;j<4;j++) acc[i][j] = (f32x4)0.f;

    for (int k0 = 0; k0 < CC; k0 += 64) {
        __syncthreads();
#pragma unroll
        for (int i=0;i<4;i++){
            int u   = (wid*4 + i)*64 + lane;
            int row = u >> 3, c = u & 7;
            int cs  = c ^ (row & 7);      // inverse-swizzled source chunk
            ASYNC16(&xb[(size_t)(m0+row)*CC + k0 + cs*8], &As[(wid*4+i)*512]);
            ASYNC16(&wT[(size_t)(n0+row)*CC + k0 + cs*8], &Bs[(wid*4+i)*512]);
        }
        __syncthreads();
#pragma unroll
        for (int ks=0;ks<2;ks++){
            bf16x8 a[4], b[4];
#pragma unroll
            for (int m=0;m<4;m++){
                int row = wr*64 + m*16 + l15;
                a[m] = *reinterpret_cast<const bf16x8*>(&As[row*64 + (((ks<<2)|lh) ^ (row&7))*8]);
            }
#pragma unroll
            for (int n=0;n<4;n++){
                int col = wc*64 + n*16 + l15;
                b[n] = *reinterpret_cast<const bf16x8*>(&Bs[col*64 + (((ks<<2)|lh) ^ (col&7))*8]);
            }
#pragma unroll
            for (int m=0;m<4;m++)
#pragma unroll
              for (int n=0;n<4;n++)
                acc[m][n] = MFMA(a[m], b[n], acc[m][n]);
        }
    }

    // epilogue: scatter into q/k/v [B,H,T,HD] bf16; fold exp2-domain scale into q
#pragma unroll
    for (int n=0;n<4;n++){
        int col = n0 + wc*64 + n*16 + l15;
        int sect = col >> 10;
        int cc = col & 1023;
        int h = cc >> 6, d = cc & 63;
        float bv = bias[col];
        short* dst = (sect==0) ? qb : (sect==1) ? kb : vb;
        float mul = (sect==0) ? QSCALE : 1.f;
#pragma unroll
        for (int m=0;m<4;m++)
#pragma unroll
          for (int r=0;r<4;r++){
            int row = m0 + wr*64 + m*16 + lh*4 + r;
            int b_ = row >> 11, tt_ = row & (TT-1);
            float v = (acc[m][n][r] + bv) * mul;
            dst[((size_t)(b_*HH + h)*TT + tt_)*HD + d] = f2bf(v);
          }
    }
}

// ---------------- Flash attention v8: UNPAIRED 128-row q-tiles (descending dispatch,
// 1024 blocks -> 3 blocks/CU), swapped QK^T, K/V via global_load_lds, cvt_pk P-pack.
__global__ __launch_bounds__(256, 3)
void attn_kernel(const short* __restrict__ qb, const short* __restrict__ kb,
                 const short* __restrict__ vtb, short* __restrict__ yb)
{
    __shared__ short Ks[2][64*64];   // [kv][d] bf16, SWZA chunk swizzle
    __shared__ short Vt[2][64*64];   // [d][kv] bf16, SWZA chunk swizzle
    __shared__ short Ps[4][32*64];   // per-wave P [qloc][kv] bf16, SWZA

    const int bh = blockIdx.x;            // 0..63 : id%8==bh%8 -> same-head blocks share XCD
    const int qt = 15 - blockIdx.y;       // descending: longest blocks dispatch first
    const int b_ = bh >> 4, h = bh & 15;
    const short* qp  = qb  + (size_t)bh*TT*HD;
    const short* kp  = kb  + (size_t)bh*TT*HD;
    const short* vtp = vtb + (size_t)bh*HD*TT;   // [d][T]
    const int t = threadIdx.x, wid = t >> 6, lane = t & 63;
    const int l15 = lane & 15, lh = lane >> 4;

    // staging map: u = (wid*2+i)*64 + lane; row = u>>3, chunk = u&7 (16B chunks)
    const int su0 = (wid*2+0)*64 + lane;
    const int su1 = (wid*2+1)*64 + lane;
    const int sr0 = su0 >> 3, sc0 = (su0 & 7) ^ (SWZA(su0 >> 3) >> 3);
    const int sr1 = su1 >> 3, sc1 = (su1 & 7) ^ (SWZA(su1 >> 3) >> 3);

    const bf16x8 ones = { 0x3F80,0x3F80,0x3F80,0x3F80,0x3F80,0x3F80,0x3F80,0x3F80 };

    auto stage = [&](int buf, int kvbase){
        ASYNC16(&kp[(size_t)(kvbase+sr0)*HD + sc0*8], &Ks[buf][(wid*2+0)*512]);
        ASYNC16(&kp[(size_t)(kvbase+sr1)*HD + sc1*8], &Ks[buf][(wid*2+1)*512]);
        ASYNC16(&vtp[(size_t)sr0*TT + kvbase + sc0*8], &Vt[buf][(wid*2+0)*512]);
        ASYNC16(&vtp[(size_t)sr1*TT + kvbase + sc1*8], &Vt[buf][(wid*2+1)*512]);
    };

    const int wq0 = qt*128 + wid*32;      // this wave's first q row

    bf16x8 qf[2][2];
#pragma unroll
    for (int m=0;m<2;m++)
#pragma unroll
      for (int ks=0;ks<2;ks++)
        qf[m][ks] = *reinterpret_cast<const bf16x8*>(
            &qp[(size_t)(wq0 + m*16 + l15)*HD + ks*32 + lh*8]);

    f32x4 po[2][4];
    f32x4 pden[2];
#pragma unroll
    for (int m=0;m<2;m++){
        pden[m] = (f32x4)0.f;
#pragma unroll
        for (int n=0;n<4;n++) po[m][n] = (f32x4)0.f;
    }

    const int ntk = 2*(qt + 1);

    stage(0, 0);
    __syncthreads();   // implicit vmcnt(0) drain before barrier

    for (int kt = 0; kt < ntk; kt++){
        const int cur = kt & 1;
        const int kv0 = kt*64;
        if (kt+1 < ntk) stage(cur ^ 1, kv0 + 64);   // fly during compute

        if (kv0 <= wq0 + 31){     // wave-uniform causal activity test
            // S^T = K Q^T : per lane q = l15 (const), kv = f*16 + lh*4 + r
            f32x4 s[2][4];
#pragma unroll
            for (int m=0;m<2;m++)
#pragma unroll
              for (int f=0;f<4;f++) s[m][f] = (f32x4)0.f;
            __builtin_amdgcn_s_setprio(1);
#pragma unroll
            for (int ks=0;ks<2;ks++){
#pragma unroll
                for (int f=0;f<4;f++){
                    int kvr = f*16 + l15;
                    bf16x8 kf = *reinterpret_cast<const bf16x8*>(
                        &Ks[cur][(kvr*64 + ks*32 + lh*8) ^ SWZA(kvr)]);
                    s[0][f] = MFMA(kf, qf[0][ks], s[0][f]);
                    s[1][f] = MFMA(kf, qf[1][ks], s[1][f]);
                }
            }
            __builtin_amdgcn_s_setprio(0);
            // causal mask (straddling tiles only): q is per-lane scalar
#pragma unroll
            for (int m=0;m<2;m++){
                if (kv0 + 63 > wq0 + m*16){
                    int qm = wq0 + m*16 + l15;
#pragma unroll
                    for (int f=0;f<4;f++)
#pragma unroll
                      for (int r=0;r<4;r++){
                        int kv = kv0 + f*16 + lh*4 + r;
                        if (kv > qm) s[m][f][r] = -1e30f;
                      }
                }
            }
            // P = exp2(S'); pack via v_cvt_pk_bf16_f32; one b64 LDS write per f
#pragma unroll
            for (int m=0;m<2;m++){
                int qloc = m*16 + l15;
                int rowswz = SWZA(qloc);
#pragma unroll
                for (int f=0;f<4;f++){
                    uint2 pk;
                    pk.x = cvtpk(exp2f(s[m][f][0]), exp2f(s[m][f][1]));
                    pk.y = cvtpk(exp2f(s[m][f][2]), exp2f(s[m][f][3]));
                    int idx = (qloc*64 + f*16 + lh*4) ^ rowswz;
                    *reinterpret_cast<uint2*>(&Ps[wid][idx]) = pk;
                }
            }
            // O += P V ; den += P * 1  (ones-column via constant B-fragment)
            __builtin_amdgcn_s_setprio(1);
#pragma unroll
            for (int ks2=0;ks2<2;ks2++){
                bf16x8 pa[2];
#pragma unroll
                for (int m=0;m<2;m++){
                    int qloc = m*16 + l15;
                    pa[m] = *reinterpret_cast<const bf16x8*>(
                        &Ps[wid][(qloc*64 + ks2*32 + lh*8) ^ SWZA(qloc)]);
                }
                pden[0] = MFMA(pa[0], ones, pden[0]);
                pden[1] = MFMA(pa[1], ones, pden[1]);
#pragma unroll
                for (int n=0;n<4;n++){
                    int dd = n*16 + l15;
                    bf16x8 vf = *reinterpret_cast<const bf16x8*>(
                        &Vt[cur][(dd*64 + ks2*32 + lh*8) ^ SWZA(dd)]);
                    po[0][n] = MFMA(pa[0], vf, po[0][n]);
                    po[1][n] = MFMA(pa[1], vf, po[1][n]);
                }
            }
            __builtin_amdgcn_s_setprio(0);
        }

        __syncthreads();   // drains staged loads (vmcnt) + publishes next buffer
    }

    // epilogue -> y [B,T,C] bf16
#pragma unroll
    for (int m=0;m<2;m++){
        float rcp[4];
#pragma unroll
        for (int r=0;r<4;r++) rcp[r] = 1.f / pden[m][r];
#pragma unroll
        for (int n=0;n<4;n++)
#pragma unroll
          for (int r=0;r<4;r++){
            int q = wq0 + m*16 + lh*4 + r;
            int dd = n*16 + l15;
            yb[(size_t)(b_*TT + q)*CC + h*HD + dd] = f2bf(po[m][n][r] * rcp[r]);
          }
    }
}

// ---------------- Output projection (bf16): y [8192,1024] @ wpT^T + bias -> fp32 out
__global__ __launch_bounds__(256, 2)
void proj_gemm(const short* __restrict__ y, const short* __restrict__ wpT,
               const float* __restrict__ bias, float* __restrict__ out)
{
    __shared__ short As[128*64];
    __shared__ short Bs[128*64];
    const int bid = blockIdx.x;
    const int swz = (bid & 7) * 64 + (bid >> 3);   // 512 blocks
    const int bm = swz >> 3, bn = swz & 7;
    const int m0 = bm*128, n0 = bn*128;
    const int t  = threadIdx.x;
    const int wid = t >> 6, lane = t & 63;
    const int wr = wid >> 1, wc = wid & 1;
    const int l15 = lane & 15, lh = lane >> 4;

    f32x4 acc[4][4];
#pragma unroll
    for (int i=0;i<4;i++)
#pragma unroll
      for (int j=0;j<4;j++) acc[i][j] = (f32x4)0.f;

    for (int k0 = 0; k0 < CC; k0 += 64) {
        __syncthreads();
#pragma unroll
        for (int i=0;i<4;i++){
            int u   = (wid*4 + i)*64 + lane;
            int row = u >> 3, c = u & 7;
            int cs  = c ^ (row & 7);
            ASYNC16(&y[(size_t)(m0+row)*CC + k0 + cs*8],   &As[(wid*4+i)*512]);
            ASYNC16(&wpT[(size_t)(n0+row)*CC + k0 + cs*8], &Bs[(wid*4+i)*512]);
        }
        __syncthreads();
#pragma unroll
        for (int ks=0;ks<2;ks++){
            bf16x8 a[4], b[4];
#pragma unroll
            for (int m=0;m<4;m++){
                int row = wr*64 + m*16 + l15;
                a[m] = *reinterpret_cast<const bf16x8*>(&As[row*64 + (((ks<<2)|lh) ^ (row&7))*8]);
            }
#pragma unroll
            for (int n=0;n<4;n++){
                int col = wc*64 + n*16 + l15;
                b[n] = *reinterpret_cast<const bf16x8*>(&Bs[col*64 + (((ks<<2)|lh) ^ (col&7))*8]);
            }
#pragma unroll
            for (int m=0;m<4;m++)
#pragma unroll
              for (int n=0;n<4;n++)
                acc[m][n] = MFMA(a[m], b[n], acc[m][n]);
        }
    }

#pragma unroll
    for (int n=0;n<4;n++){
        int col = n0 + wc*64 + n*16 + l15;
        float bv = bias[col];
#pragma unroll
        for (int m=0;m<4;m++)
#pragma unroll
          for (int r=0;r<4;r++){
            int row = m0 + wr*64 + m*16 + lh*4 + r;
            out[(size_t)row*CC + col] = acc[m][n][r] + bv;
          }
    }
}

extern "C" void kernel_launch(void* const* d_in, const int* in_sizes, int n_in,
                              void* d_out, int out_size, void* d_ws, size_t ws_size,
                              hipStream_t stream) {
    const float* x      = (const float*)d_in[0];
    const float* w_attn = (const float*)d_in[1];
    const float* b_attn = (const float*)d_in[2];
    const float* w_proj = (const float*)d_in[3];
    const float* b_proj = (const float*)d_in[4];
    float* out = (float*)d_out;

    const size_t S = (size_t)BB*TT*CC;   // 8.4M elems
    short* qb  = (short*)d_ws;           // bf16 [B,H,T,HD]
    short* kb  = qb + S;
    short* vb  = kb + S;
    short* yx  = vb + S;                 // x-bf16 during prepass+qkv; y-bf16 after attn
    short* wT  = yx + S;                 // bf16 [3072][1024]
    short* wpT = wT + (size_t)NQ*CC;     // bf16 [1024][1024]
    short* vtb = wpT + (size_t)CC*CC;    // bf16 [B,H,HD,T]  (V transposed per head)

    convert_x<<<dim3(S/(256*8)), 256, 0, stream>>>(x, yx);
    transpose_w<<<dim3(CC/64, NQ/64), 256, 0, stream>>>(w_attn, wT, NQ);
    transpose_w<<<dim3(CC/64, CC/64), 256, 0, stream>>>(w_proj, wpT, CC);
    qkv_gemm<<<dim3((BB*TT/128)*(NQ/128)), 256, 0, stream>>>(yx, wT, b_attn, qb, kb, vb);
    transpose_v<<<dim3(BB*HH, TT/64), 256, 0, stream>>>(vb, vtb);
    attn_kernel<<<dim3(BB*HH, TT/128), 256, 0, stream>>>(qb, kb, vtb, yx);
    proj_gemm<<<dim3((BB*TT/128)*(CC/128)), 256, 0, stream>>>(yx, wpT, b_proj, out);
}